// Round 6
// baseline (840.222 us; speedup 1.0000x reference)
//
#include <hip/hip_runtime.h>
#include <stdint.h>

#define HCH 256
#define GEO 13
#define DEPTH 3
#define EPSBN 1e-5f
#define MFMA __builtin_amdgcn_mfma_f32_16x16x32_bf16

typedef __attribute__((ext_vector_type(8))) short short8;
typedef __attribute__((ext_vector_type(4))) float floatx4;

// fp32 -> bf16 RNE
__device__ __forceinline__ short f2bs(float f) {
    unsigned u = __float_as_uint(f);
    unsigned r = (u + 0x7fffu + ((u >> 16) & 1u)) >> 16;
    return (short)r;
}
// pack two fp32 -> bf16 pair (lo = a, hi = b)
__device__ __forceinline__ unsigned pk2(float a, float b) {
    unsigned ua = __float_as_uint(a); ua = (ua + 0x7fffu + ((ua >> 16) & 1u)) >> 16;
    unsigned ub = __float_as_uint(b); ub = (ub + 0x7fffu + ((ub >> 16) & 1u)) & 0xffff0000u;
    return (ua & 0xffffu) | ub;
}

// ---------------- k_zero ----------------
__global__ void k_zero(float4* out4, int n4, int* cnt) {
    int i = blockIdx.x * blockDim.x + threadIdx.x;
    if (i < n4) out4[i] = make_float4(0.f, 0.f, 0.f, 0.f);
    if (blockIdx.x == 0 && threadIdx.x < 4) cnt[threadIdx.x] = 0;
}

// ---------------- k_prep: BN-scale folded into weights; offsets; bf16 inputs; compaction
// W0t: [(br*25 + c)*256 + n]*32 + kk  (bf16), K 781 + offset-row 781 + pad->800
// Wht: [((br*3 + lh)*8 + c)*256 + n]*32 + kk (bf16), scale (and att for lh==2) folded
// of:  (br*4 + l)*256 + col  (l=1..3 used; l==3 has att folded)
// node_bf: [N][256] bf16 ; geo_bf: [E][32] bf16, col 13 = 1.0 (offset row), rest pad 0
__global__ void k_prep(const float* __restrict__ W0, const float* __restrict__ Wh,
                       const float* __restrict__ b0, const float* __restrict__ bh,
                       const float* __restrict__ gm, const float* __restrict__ bt,
                       const float* __restrict__ mn, const float* __restrict__ vr,
                       const float* __restrict__ att,
                       const float* __restrict__ node, const float* __restrict__ geo,
                       const int* __restrict__ edx_ij, const int* __restrict__ edx_jk,
                       const int* __restrict__ nei_p,
                       short* __restrict__ W0t, short* __restrict__ Wht,
                       float* __restrict__ sc, float* __restrict__ of,
                       short* __restrict__ node_bf, short* __restrict__ geo_bf,
                       int* __restrict__ lists, int* __restrict__ cnt,
                       int E, int d_in_dim, int nb_node, int nb_geo) {
    const int B_W0 = 100, B_WH = 96, B_SC = 16;
    __shared__ short s[32][256];
    int b = blockIdx.x, t = threadIdx.x;
    if (b < B_W0) {
        int c = b % 25, br = b / 25;
        int gi = (br * (DEPTH + 1)) * HCH + t;
        float s0 = gm[gi] * rsqrtf(vr[gi] + EPSBN);
        float of0 = (b0[br * HCH + t] - mn[gi]) * s0 + bt[gi];
        #pragma unroll
        for (int kk = 0; kk < 32; ++kk) {
            int kidx = c * 32 + kk;
            float v = (kidx < d_in_dim) ? W0[((size_t)br * d_in_dim + kidx) * HCH + t] * s0
                    : ((kidx == d_in_dim) ? of0 : 0.f);
            s[kk][t] = f2bs(v);
        }
        __syncthreads();
        size_t obase = ((size_t)b * 256 + t) * 32;
        #pragma unroll
        for (int g = 0; g < 4; ++g) {
            short8 v;
            #pragma unroll
            for (int j = 0; j < 8; ++j) v[j] = s[g * 8 + j][t];
            *reinterpret_cast<short8*>(W0t + obase + g * 8) = v;
        }
    } else if (b < B_W0 + B_WH) {
        int idx = b - B_W0;
        int c = idx & 7; idx >>= 3;
        int lh = idx % 3, br = idx / 3;
        int gi = (br * (DEPTH + 1) + lh + 1) * HCH + t;
        float sl = gm[gi] * rsqrtf(vr[gi] + EPSBN);
        if (lh == 2) sl *= att[br];
        #pragma unroll
        for (int kk = 0; kk < 32; ++kk) {
            float v = Wh[((size_t)(br * DEPTH + lh) * HCH + (c * 32 + kk)) * HCH + t] * sl;
            s[kk][t] = f2bs(v);
        }
        __syncthreads();
        size_t obase = ((size_t)(b - B_W0) * 256 + t) * 32;
        #pragma unroll
        for (int g = 0; g < 4; ++g) {
            short8 v;
            #pragma unroll
            for (int j = 0; j < 8; ++j) v[j] = s[g * 8 + j][t];
            *reinterpret_cast<short8*>(Wht + obase + g * 8) = v;
        }
    } else if (b < B_W0 + B_WH + B_SC) {
        int idx = (b - B_W0 - B_WH) * 256 + t;
        int col = idx & 255, l = (idx >> 8) & 3, br = idx >> 10;
        int gi = (br * (DEPTH + 1) + l) * HCH + col;
        float sA = gm[gi] * rsqrtf(vr[gi] + EPSBN);
        float bias = (l == 0) ? b0[br * HCH + col] : bh[(br * DEPTH + (l - 1)) * HCH + col];
        float ofv = (bias - mn[gi]) * sA + bt[gi];
        if (l == 3) ofv *= att[br];     // scale itself folded into W; offset carries att
        sc[idx] = sA;
        of[idx] = ofv;
    } else if (b < B_W0 + B_WH + B_SC + nb_node) {
        size_t i = ((size_t)(b - B_W0 - B_WH - B_SC) * 256 + t) * 8;
        const float4* src = reinterpret_cast<const float4*>(node + i);
        float4 v0 = src[0], v1 = src[1];
        short8 pk;
        pk[0] = f2bs(v0.x); pk[1] = f2bs(v0.y); pk[2] = f2bs(v0.z); pk[3] = f2bs(v0.w);
        pk[4] = f2bs(v1.x); pk[5] = f2bs(v1.y); pk[6] = f2bs(v1.z); pk[7] = f2bs(v1.w);
        *reinterpret_cast<short8*>(node_bf + i) = pk;
    } else if (b < B_W0 + B_WH + B_SC + nb_node + nb_geo) {
        int i = (b - B_W0 - B_WH - B_SC - nb_node) * 256 + t;
        int e = i >> 2, cc = i & 3;
        if (e < E) {
            short8 pk;
            #pragma unroll
            for (int j = 0; j < 8; ++j) {
                int col = cc * 8 + j;
                pk[j] = (col < GEO) ? f2bs(geo[(size_t)e * GEO + col])
                      : ((col == GEO) ? (short)0x3F80 : (short)0);   // 1.0 at offset row
            }
            *reinterpret_cast<short8*>(geo_bf + (size_t)e * 32 + cc * 8) = pk;
        }
    } else {
        int e = (b - (B_W0 + B_WH + B_SC + nb_node + nb_geo)) * 256 + t;
        int NEI = nei_p[0];
        int lane = t & 63;
        int br = -1;
        if (e < E)
            br = ((edx_ij[e] < NEI) ? 0 : 2) + ((edx_jk[e] < NEI) ? 0 : 1);
        unsigned long long lt = (lane == 63) ? 0x7fffffffffffffffull
                                             : ((1ull << lane) - 1ull);
        #pragma unroll
        for (int bb = 0; bb < 4; ++bb) {
            unsigned long long mk = __ballot(br == bb);
            if (mk) {
                int leader = __ffsll((long long)mk) - 1;
                int base = 0;
                if (lane == leader) base = atomicAdd(&cnt[bb], (int)__popcll(mk));
                base = __shfl(base, leader);
                if (br == bb) {
                    int pos = base + (int)__popcll(mk & lt);
                    lists[(size_t)bb * E + pos] = e;
                }
            }
        }
    }
}

// ---------------- k_main: one wave = 32 edges; transposed GEMMs; per-wave LDS hand-off --
// D[m=outcol][n=edge] = W^T x X^T. No __syncthreads (waves fully independent).
// Inter-layer: epilogue ds_writes h (D-layout) into per-wave H; chunk loop ds_reads
// B-frags (edge=l16, k=quad*8+j). Same-wave LDS RAW -> s_waitcnt lgkmcnt(0) only.
__global__ __launch_bounds__(256, 2)
void k_main(const short* __restrict__ node_bf, const short* __restrict__ geo_bf,
            const int* __restrict__ eidx,
            const short* __restrict__ W0t, const short* __restrict__ Wht,
            const float* __restrict__ of,
            const int* __restrict__ lists, const int* __restrict__ cnt,
            float* __restrict__ out, int E) {
    __shared__ __align__(16) short H[4][32][264];   // 67.6 KB, one 16.9 KB slab per wave
    int t = threadIdx.x;
    short (*Hw)[264] = H[t >> 6];

    int wid = blockIdx.x * 4 + (t >> 6);
    int c0 = cnt[0], c1 = cnt[1], c2 = cnt[2], c3 = cnt[3];
    int n0 = (c0 + 31) >> 5, n1 = (c1 + 31) >> 5, n2 = (c2 + 31) >> 5, n3 = (c3 + 31) >> 5;
    int br, tile, cb;
    if (wid < n0)                     { br = 0; tile = wid;                cb = c0; }
    else if (wid < n0 + n1)           { br = 1; tile = wid - n0;           cb = c1; }
    else if (wid < n0 + n1 + n2)      { br = 2; tile = wid - n0 - n1;      cb = c2; }
    else if (wid < n0 + n1 + n2 + n3) { br = 3; tile = wid - n0 - n1 - n2; cb = c3; }
    else return;                                     // no barriers -> early return safe
    int m = cb - tile * 32; if (m > 32) m = 32;
    int lane = t & 63, quad = lane >> 4, l16 = lane & 15;

    const int* lb = lists + (size_t)br * E + tile * 32;
    int e0 = lb[(l16 < m) ? l16 : 0];
    int e1 = lb[(16 + l16 < m) ? (16 + l16) : 0];
    bool v0 = (l16 < m), v1 = (16 + l16 < m);
    size_t i0 = (size_t)eidx[e0],       i1 = (size_t)eidx[e1];
    size_t j0 = (size_t)eidx[E + e0],   j1 = (size_t)eidx[E + e1];
    size_t k0 = (size_t)eidx[2*E + e0], k1 = (size_t)eidx[2*E + e1];

    floatx4 acc[2][16];          // lives in AGPR half of the unified file
    const floatx4 zf = {0.f, 0.f, 0.f, 0.f};

    // per-chunk gemm over 16 col-tiles, A-frags (weights, L2-hot) in batches of 4
    auto gemm_chunk = [&](const short* Wc0, short8 bf0, short8 bf1, bool first) {
        const short* Wc = Wc0 + l16 * 32 + quad * 8;
        #pragma unroll
        for (int cb4 = 0; cb4 < 4; ++cb4) {
            short8 a[4];
            #pragma unroll
            for (int u = 0; u < 4; ++u)
                a[u] = *reinterpret_cast<const short8*>(Wc + (cb4 * 4 + u) * 512);
            #pragma unroll
            for (int u = 0; u < 4; ++u) {
                int ix = cb4 * 4 + u;
                if (first) {
                    acc[0][ix] = MFMA(a[u], bf0, zf, 0, 0, 0);
                    acc[1][ix] = MFMA(a[u], bf1, zf, 0, 0, 0);
                } else {
                    acc[0][ix] = MFMA(a[u], bf0, acc[0][ix], 0, 0, 0);
                    acc[1][ix] = MFMA(a[u], bf1, acc[1][ix], 0, 0, 0);
                }
            }
        }
    };

    // ---------------- layer 0: B-frags gathered straight from global ----------------
    const short* W0b = W0t + (size_t)br * 25 * 8192;
    auto l0addr = [&](int c, int g) -> const short* {
        if (c < 8)  return node_bf + (g ? i1 : i0) * HCH + c * 32 + quad * 8;
        if (c < 16) return node_bf + (g ? j1 : j0) * HCH + (c - 8) * 32 + quad * 8;
        if (c < 24) return node_bf + (g ? k1 : k0) * HCH + (c - 16) * 32 + quad * 8;
        return geo_bf + (size_t)(g ? e1 : e0) * 32 + quad * 8;
    };
    short8 bg[3][2];             // depth-2 gather pipeline
    bg[0][0] = *reinterpret_cast<const short8*>(l0addr(0, 0));
    bg[0][1] = *reinterpret_cast<const short8*>(l0addr(0, 1));
    bg[1][0] = *reinterpret_cast<const short8*>(l0addr(1, 0));
    bg[1][1] = *reinterpret_cast<const short8*>(l0addr(1, 1));
    #pragma unroll
    for (int c = 0; c < 25; ++c) {
        if (c + 2 < 25) {
            bg[(c + 2) % 3][0] = *reinterpret_cast<const short8*>(l0addr(c + 2, 0));
            bg[(c + 2) % 3][1] = *reinterpret_cast<const short8*>(l0addr(c + 2, 1));
        }
        gemm_chunk(W0b + (size_t)c * 8192, bg[c % 3][0], bg[c % 3][1], c == 0);
    }

    // ---------------- hidden layers 1..3: LDS round-trip hand-off ----------------
    #pragma unroll
    for (int lh = 0; lh < 3; ++lh) {
        // epilogue: relu(+offset for lh>0; lh==0 offset came via K-row) -> bf16 -> LDS
        #pragma unroll
        for (int ct = 0; ct < 16; ++ct) {
            float4 o = make_float4(0.f, 0.f, 0.f, 0.f);
            if (lh > 0)
                o = *reinterpret_cast<const float4*>(
                        of + (br * 4 + lh) * HCH + ct * 16 + quad * 4);
            #pragma unroll
            for (int g = 0; g < 2; ++g) {
                unsigned p0 = pk2(fmaxf(acc[g][ct][0] + o.x, 0.f),
                                  fmaxf(acc[g][ct][1] + o.y, 0.f));
                unsigned p1 = pk2(fmaxf(acc[g][ct][2] + o.z, 0.f),
                                  fmaxf(acc[g][ct][3] + o.w, 0.f));
                *reinterpret_cast<uint2*>(&Hw[g * 16 + l16][ct * 16 + quad * 4]) =
                    make_uint2(p0, p1);
            }
        }
        __asm__ volatile("s_waitcnt lgkmcnt(0)" ::: "memory");  // same-wave LDS RAW
        const short* Wl = Wht + (size_t)((br * 3 + lh) * 8) * 8192;
        #pragma unroll
        for (int c = 0; c < 8; ++c) {
            short8 b0 = *reinterpret_cast<const short8*>(&Hw[l16][c * 32 + quad * 8]);
            short8 b1 = *reinterpret_cast<const short8*>(&Hw[16 + l16][c * 32 + quad * 8]);
            gemm_chunk(Wl + (size_t)c * 8192, b0, b1, c == 0);
        }
    }

    // ---------------- final epilogue: relu(+of3, att folded) -> atomic scatter -------
    float* o0 = out + i0 * HCH;
    float* o1 = out + i1 * HCH;
    #pragma unroll
    for (int ct = 0; ct < 16; ++ct) {
        float4 o = *reinterpret_cast<const float4*>(
                       of + (br * 4 + 3) * HCH + ct * 16 + quad * 4);
        #pragma unroll
        for (int r = 0; r < 4; ++r) {
            float ov = (r == 0) ? o.x : (r == 1) ? o.y : (r == 2) ? o.z : o.w;
            float h0 = fmaxf(acc[0][ct][r] + ov, 0.f);
            float h1 = fmaxf(acc[1][ct][r] + ov, 0.f);
            int col = ct * 16 + quad * 4 + r;
            if (v0) atomicAdd(o0 + col, h0);
            if (v1) atomicAdd(o1 + col, h1);
        }
    }
}

// ---------------- host launcher ----------------
extern "C" void kernel_launch(void* const* d_in, const int* in_sizes, int n_in,
                              void* d_out, int out_size, void* d_ws, size_t ws_size,
                              hipStream_t stream) {
    const float* node  = (const float*)d_in[0];
    const float* geo   = (const float*)d_in[1];
    const int*   eidx  = (const int*)d_in[2];
    const int*   edxij = (const int*)d_in[3];
    const int*   edxjk = (const int*)d_in[4];
    const float* att   = (const float*)d_in[5];
    const float* W0    = (const float*)d_in[6];
    const float* b0    = (const float*)d_in[7];
    const float* Wh    = (const float*)d_in[8];
    const float* bh    = (const float*)d_in[9];
    const float* gm    = (const float*)d_in[10];
    const float* bt    = (const float*)d_in[11];
    const float* mn    = (const float*)d_in[12];
    const float* vr    = (const float*)d_in[13];
    const int*   neip  = (const int*)d_in[14];

    int E = in_sizes[3];
    int N = in_sizes[0] / HCH;
    int d_in_dim = in_sizes[6] / (4 * HCH);   // 781

    uint8_t* w = (uint8_t*)d_ws;
    size_t off = 0;
    short* W0t  = (short*)(w + off); off += (size_t)4 * 25 * 256 * 32 * 2;
    short* Wht  = (short*)(w + off); off += (size_t)4 * 3 * 8 * 256 * 32 * 2;
    float* sc   = (float*)(w + off); off += 4096 * 4;
    float* of   = (float*)(w + off); off += 4096 * 4;
    int*   lists= (int*)(w + off);   off += (size_t)4 * E * 4;
    int*   cnt  = (int*)(w + off);   off += 16;
    short* node_bf = (short*)(w + off); off += (size_t)N * HCH * 2;
    short* geo_bf  = (short*)(w + off); off += (size_t)E * 32 * 2;

    float* out = (float*)d_out;
    int n4 = out_size / 4;
    k_zero<<<(n4 + 255) / 256, 256, 0, stream>>>((float4*)out, n4, cnt);

    int nb_node = N / 8;
    int nb_geo  = (4 * E + 255) / 256;
    int nb_cmp  = (E + 255) / 256;
    k_prep<<<100 + 96 + 16 + nb_node + nb_geo + nb_cmp, 256, 0, stream>>>(
        W0, Wh, b0, bh, gm, bt, mn, vr, att, node, geo, edxij, edxjk, neip,
        W0t, Wht, sc, of, node_bf, geo_bf, lists, cnt, E, d_in_dim, nb_node, nb_geo);

    int maxT = (E + 31) / 32 + 4;           // max tiles across 4 branches
    int blocks = (maxT + 3) / 4;            // 4 independent waves per block
    k_main<<<blocks, 256, 0, stream>>>(node_bf, geo_bf, eidx, W0t, Wht,
                                       of, lists, cnt, out, E);
}

// Round 7
// 384.501 us; speedup vs baseline: 2.1852x; 2.1852x over previous
//
#include <hip/hip_runtime.h>
#include <hip/hip_bf16.h>
#include <stdint.h>

#define HCH 256
#define GEO 13
#define DEPTH 3
#define EPSBN 1e-5f
#define MFMA __builtin_amdgcn_mfma_f32_16x16x32_bf16

typedef __attribute__((ext_vector_type(8))) short short8;
typedef __attribute__((ext_vector_type(4))) float floatx4;

// fp32 -> bf16 RNE
__device__ __forceinline__ short f2bs(float f) {
    unsigned u = __float_as_uint(f);
    unsigned r = (u + 0x7fffu + ((u >> 16) & 1u)) >> 16;
    return (short)r;
}

// ---------------- k_zero: zero output + branch counters ----------------
__global__ void k_zero(float4* out4, int n4, int* cnt) {
    int i = blockIdx.x * blockDim.x + threadIdx.x;
    if (i < n4) out4[i] = make_float4(0.f, 0.f, 0.f, 0.f);
    if (blockIdx.x == 0 && threadIdx.x < 4) cnt[threadIdx.x] = 0;
}

// ---------------- k_prep: weights->bf16 (transposed), node/geo->bf16, BN fold, compaction
// W0t: [(br*25 + c)*256 + n]*32 + kk  (bf16), K padded 781->800
// Wht: [((br*3 + l)*8 + c)*256 + n]*32 + kk
// sc/of: (br*4 + layer)*256 + col   (layer 3 pre-multiplied by att[br])
// node_bf: [N][256] bf16 ; geo_bf: [E][32] bf16 zero-padded
__global__ void k_prep(const float* __restrict__ W0, const float* __restrict__ Wh,
                       const float* __restrict__ b0, const float* __restrict__ bh,
                       const float* __restrict__ gm, const float* __restrict__ bt,
                       const float* __restrict__ mn, const float* __restrict__ vr,
                       const float* __restrict__ att,
                       const float* __restrict__ node, const float* __restrict__ geo,
                       const int* __restrict__ edx_ij, const int* __restrict__ edx_jk,
                       const int* __restrict__ nei_p,
                       short* __restrict__ W0t, short* __restrict__ Wht,
                       float* __restrict__ sc, float* __restrict__ of,
                       short* __restrict__ node_bf, short* __restrict__ geo_bf,
                       int* __restrict__ lists, int* __restrict__ cnt,
                       int E, int d_in_dim, int nb_node, int nb_geo) {
    const int B_W0 = 100, B_WH = 96, B_SC = 16;
    __shared__ short s[32][256];
    int b = blockIdx.x, t = threadIdx.x;
    if (b < B_W0) {
        int c = b % 25, br = b / 25;
        #pragma unroll
        for (int kk = 0; kk < 32; ++kk) {
            int kidx = c * 32 + kk;
            float v = (kidx < d_in_dim) ? W0[((size_t)br * d_in_dim + kidx) * HCH + t] : 0.f;
            s[kk][t] = f2bs(v);   // coalesced global read (n fastest)
        }
        __syncthreads();
        size_t obase = ((size_t)(b) * 256 + t) * 32;
        #pragma unroll
        for (int g = 0; g < 4; ++g) {
            short8 v;
            #pragma unroll
            for (int j = 0; j < 8; ++j) v[j] = s[g * 8 + j][t];
            *reinterpret_cast<short8*>(W0t + obase + g * 8) = v;
        }
    } else if (b < B_W0 + B_WH) {
        int idx = b - B_W0;
        int c = idx & 7; idx >>= 3;
        int l = idx % 3, br = idx / 3;
        #pragma unroll
        for (int kk = 0; kk < 32; ++kk) {
            float v = Wh[((size_t)(br * DEPTH + l) * HCH + (c * 32 + kk)) * HCH + t];
            s[kk][t] = f2bs(v);
        }
        __syncthreads();
        size_t obase = ((size_t)(b - B_W0) * 256 + t) * 32;
        #pragma unroll
        for (int g = 0; g < 4; ++g) {
            short8 v;
            #pragma unroll
            for (int j = 0; j < 8; ++j) v[j] = s[g * 8 + j][t];
            *reinterpret_cast<short8*>(Wht + obase + g * 8) = v;
        }
    } else if (b < B_W0 + B_WH + B_SC) {
        int idx = (b - B_W0 - B_WH) * 256 + t; // 4096 elems
        int col = idx & 255, l = (idx >> 8) & 3, br = idx >> 10;
        int gi = (br * (DEPTH + 1) + l) * HCH + col;
        float sA = gm[gi] * rsqrtf(vr[gi] + EPSBN);
        float bias = (l == 0) ? b0[br * HCH + col] : bh[(br * DEPTH + (l - 1)) * HCH + col];
        float ofv = (bias - mn[gi]) * sA + bt[gi];
        if (l == 3) { float av = att[br]; sA *= av; ofv *= av; }  // fold att (relu out >=0)
        sc[idx] = sA;
        of[idx] = ofv;
    } else if (b < B_W0 + B_WH + B_SC + nb_node) {
        // node fp32 -> bf16, 8 elems/thread, coalesced
        size_t i = ((size_t)(b - B_W0 - B_WH - B_SC) * 256 + t) * 8;
        const float4* src = reinterpret_cast<const float4*>(node + i);
        float4 v0 = src[0], v1 = src[1];
        short8 pk;
        pk[0] = f2bs(v0.x); pk[1] = f2bs(v0.y); pk[2] = f2bs(v0.z); pk[3] = f2bs(v0.w);
        pk[4] = f2bs(v1.x); pk[5] = f2bs(v1.y); pk[6] = f2bs(v1.z); pk[7] = f2bs(v1.w);
        *reinterpret_cast<short8*>(node_bf + i) = pk;
    } else if (b < B_W0 + B_WH + B_SC + nb_node + nb_geo) {
        // geo [E][13] fp32 -> [E][32] bf16 zero-padded
        int i = (b - B_W0 - B_WH - B_SC - nb_node) * 256 + t;
        int e = i >> 2, cc = i & 3;
        if (e < E) {
            short8 pk;
            #pragma unroll
            for (int j = 0; j < 8; ++j) {
                int col = cc * 8 + j;
                pk[j] = (col < GEO) ? f2bs(geo[(size_t)e * GEO + col]) : (short)0;
            }
            *reinterpret_cast<short8*>(geo_bf + (size_t)e * 32 + cc * 8) = pk;
        }
    } else {
        // wave-aggregated branch compaction (4 atomics per wave)
        int e = (b - (B_W0 + B_WH + B_SC + nb_node + nb_geo)) * 256 + t;
        int NEI = nei_p[0];
        int lane = t & 63;
        int br = -1;
        if (e < E)
            br = ((edx_ij[e] < NEI) ? 0 : 2) + ((edx_jk[e] < NEI) ? 0 : 1);
        unsigned long long lt = (lane == 63) ? 0x7fffffffffffffffull
                                             : ((1ull << lane) - 1ull);
        #pragma unroll
        for (int bb = 0; bb < 4; ++bb) {
            unsigned long long mk = __ballot(br == bb);
            if (mk) {
                int leader = __ffsll((long long)mk) - 1;
                int base = 0;
                if (lane == leader) base = atomicAdd(&cnt[bb], (int)__popcll(mk));
                base = __shfl(base, leader);
                if (br == bb) {
                    int pos = base + (int)__popcll(mk & lt);
                    lists[(size_t)bb * E + pos] = e;
                }
            }
        }
    }
}

// ---------------- k_main: 64-edge tile, 8 waves (64x32 each), pipelined gathers ----------
// Structure = round-3 (best known). New: (1) part p+1's node gathers issue right after
// part p's publish barrier (latency hidden behind a full 8-chunk compute phase);
// (2) 2-deep B prefetch ring (unrolled so the ring stays in registers).
__global__ __launch_bounds__(512)
void k_main(const short* __restrict__ node_bf, const short* __restrict__ geo_bf,
            const int* __restrict__ eidx,
            const short* __restrict__ W0t, const short* __restrict__ Wht,
            const float* __restrict__ sc, const float* __restrict__ of,
            const int* __restrict__ lists, const int* __restrict__ cnt,
            float* __restrict__ out, int E) {
    __shared__ __align__(16) short A[64][264];   // 33.8 KB
    __shared__ int s_i[64];
    __shared__ int s_jk[2][64];
    __shared__ int s_e[64];

    int c0 = cnt[0], c1 = cnt[1], c2 = cnt[2], c3 = cnt[3];
    int t0 = (c0 + 63) >> 6, t1 = (c1 + 63) >> 6, t2 = (c2 + 63) >> 6, t3 = (c3 + 63) >> 6;
    int b = blockIdx.x;
    int br, tile, count;
    if (b < t0)                     { br = 0; tile = b;                count = c0; }
    else if (b < t0 + t1)           { br = 1; tile = b - t0;           count = c1; }
    else if (b < t0 + t1 + t2)      { br = 2; tile = b - t0 - t1;      count = c2; }
    else if (b < t0 + t1 + t2 + t3) { br = 3; tile = b - t0 - t1 - t2; count = c3; }
    else return;
    int m = count - tile * 64; if (m > 64) m = 64;

    int t = threadIdx.x;
    if (t < 64) {
        int e = (t < m) ? lists[(size_t)br * E + (size_t)tile * 64 + t] : 0;
        s_e[t] = (t < m) ? e : -1;
        s_i[t] = eidx[e];
        s_jk[0][t] = eidx[E + e];
        s_jk[1][t] = eidx[2 * E + e];
    }
    __syncthreads();   // indices visible

    int wv = t >> 6, lane = t & 63, quad = lane >> 4, l16 = lane & 15;
    int rbase = t >> 5, cc8 = (t & 31) * 8;   // staging coords: rows it*16+rbase, 16B piece

    floatx4 acc[4][2];
    #pragma unroll
    for (int rt = 0; rt < 4; ++rt)
        #pragma unroll
        for (int ct = 0; ct < 2; ++ct)
            #pragma unroll
            for (int r = 0; r < 4; ++r) acc[rt][ct][r] = 0.f;

    int boff[2];
    #pragma unroll
    for (int ct = 0; ct < 2; ++ct)
        boff[ct] = (wv * 32 + ct * 16 + l16) * 32 + quad * 8;

    // 8-chunk gemm with 2-deep B prefetch ring (fully unrolled -> ring in registers)
    auto do_chunks8 = [&](const short* Wbase) {
        short8 bb[3][2];
        #pragma unroll
        for (int ct = 0; ct < 2; ++ct) {
            bb[0][ct] = *reinterpret_cast<const short8*>(Wbase + boff[ct]);
            bb[1][ct] = *reinterpret_cast<const short8*>(Wbase + 8192 + boff[ct]);
        }
        #pragma unroll
        for (int c = 0; c < 8; ++c) {
            if (c + 2 < 8) {
                const short* Bn = Wbase + (size_t)(c + 2) * 8192;
                #pragma unroll
                for (int ct = 0; ct < 2; ++ct)
                    bb[(c + 2) % 3][ct] = *reinterpret_cast<const short8*>(Bn + boff[ct]);
            }
            short8 af[4];
            #pragma unroll
            for (int rt = 0; rt < 4; ++rt)
                af[rt] = *reinterpret_cast<const short8*>(&A[rt * 16 + l16][c * 32 + quad * 8]);
            #pragma unroll
            for (int rt = 0; rt < 4; ++rt)
                #pragma unroll
                for (int ct = 0; ct < 2; ++ct)
                    acc[rt][ct] = MFMA(af[rt], bb[c % 3][ct], acc[rt][ct], 0, 0, 0);
        }
    };
    // single chunk (geo part)
    auto do_chunk1 = [&](const short* Wbase) {
        short8 bc[2];
        #pragma unroll
        for (int ct = 0; ct < 2; ++ct)
            bc[ct] = *reinterpret_cast<const short8*>(Wbase + boff[ct]);
        short8 af[4];
        #pragma unroll
        for (int rt = 0; rt < 4; ++rt)
            af[rt] = *reinterpret_cast<const short8*>(&A[rt * 16 + l16][quad * 8]);
        #pragma unroll
        for (int rt = 0; rt < 4; ++rt)
            #pragma unroll
            for (int ct = 0; ct < 2; ++ct)
                acc[rt][ct] = MFMA(af[rt], bc[ct], acc[rt][ct], 0, 0, 0);
    };

    // ---------------- layer 0: gathers pre-issued one part ahead ----------------
    short8 g[2][4];    // ping-pong gather regs (part p in g[p&1])
    short8 ggeo;
    {
        #pragma unroll
        for (int it = 0; it < 4; ++it)
            g[0][it] = *reinterpret_cast<const short8*>(
                node_bf + (size_t)s_i[it * 16 + rbase] * HCH + cc8);
    }
    int grow = t >> 2, gcc = t & 3;   // geo staging coords (t<256)
    for (int p = 0; p < 4; ++p) {
        __syncthreads();               // WAR: part p-1's A reads done
        if (p < 3) {
            #pragma unroll
            for (int it = 0; it < 4; ++it)
                *reinterpret_cast<short8*>(&A[it * 16 + rbase][cc8]) = g[p & 1][it];
        } else if (t < 256) {
            *reinterpret_cast<short8*>(&A[grow][gcc * 8]) = ggeo;
        }
        __syncthreads();               // publish part p
        // issue next part's gathers (completes behind this part's 8-chunk compute)
        if (p < 2) {
            const int* idxs = s_jk[p];
            #pragma unroll
            for (int it = 0; it < 4; ++it)
                g[(p + 1) & 1][it] = *reinterpret_cast<const short8*>(
                    node_bf + (size_t)idxs[it * 16 + rbase] * HCH + cc8);
        } else if (p == 2 && t < 256) {
            int e = s_e[grow];
            if (e >= 0)
                ggeo = *reinterpret_cast<const short8*>(geo_bf + (size_t)e * 32 + gcc * 8);
            else {
                #pragma unroll
                for (int j = 0; j < 8; ++j) ggeo[j] = 0;
            }
        }
        if (p < 3) do_chunks8(W0t + (size_t)(br * 25 + p * 8) * 8192);
        else       do_chunk1(W0t + (size_t)(br * 25 + 24) * 8192);
    }

    // ---------------- BN+relu epilogues, hidden layers, final scatter ----------------
    for (int l = 0; l < 4; ++l) {
        float sv[2], ov[2];
        #pragma unroll
        for (int ct = 0; ct < 2; ++ct) {
            int col = wv * 32 + ct * 16 + l16;
            sv[ct] = sc[(br * 4 + l) * HCH + col];
            ov[ct] = of[(br * 4 + l) * HCH + col];
        }
        if (l < 3) {
            __syncthreads();  // matmul's A reads done before overwrite
            #pragma unroll
            for (int rt = 0; rt < 4; ++rt)
                #pragma unroll
                for (int ct = 0; ct < 2; ++ct) {
                    int col = wv * 32 + ct * 16 + l16;
                    #pragma unroll
                    for (int r = 0; r < 4; ++r) {
                        float h = fmaxf(acc[rt][ct][r] * sv[ct] + ov[ct], 0.f);
                        A[rt * 16 + quad * 4 + r][col] = f2bs(h);
                        acc[rt][ct][r] = 0.f;
                    }
                }
            __syncthreads();
            do_chunks8(Wht + (size_t)((br * 3 + l) * 8) * 8192);
        } else {
            // final: relu (leaky+att folded into sc/of) -> scatter-add on node i
            #pragma unroll
            for (int rt = 0; rt < 4; ++rt)
                #pragma unroll
                for (int r = 0; r < 4; ++r) {
                    int row = rt * 16 + quad * 4 + r;
                    if (row < m) {
                        float* orow = out + (size_t)s_i[row] * HCH + wv * 32 + l16;
                        #pragma unroll
                        for (int ct = 0; ct < 2; ++ct) {
                            float h = fmaxf(acc[rt][ct][r] * sv[ct] + ov[ct], 0.f);
                            atomicAdd(orow + ct * 16, h);
                        }
                    }
                }
        }
    }
}

// ---------------- host launcher ----------------
extern "C" void kernel_launch(void* const* d_in, const int* in_sizes, int n_in,
                              void* d_out, int out_size, void* d_ws, size_t ws_size,
                              hipStream_t stream) {
    const float* node  = (const float*)d_in[0];
    const float* geo   = (const float*)d_in[1];
    const int*   eidx  = (const int*)d_in[2];
    const int*   edxij = (const int*)d_in[3];
    const int*   edxjk = (const int*)d_in[4];
    const float* att   = (const float*)d_in[5];
    const float* W0    = (const float*)d_in[6];
    const float* b0    = (const float*)d_in[7];
    const float* Wh    = (const float*)d_in[8];
    const float* bh    = (const float*)d_in[9];
    const float* gm    = (const float*)d_in[10];
    const float* bt    = (const float*)d_in[11];
    const float* mn    = (const float*)d_in[12];
    const float* vr    = (const float*)d_in[13];
    const int*   neip  = (const int*)d_in[14];

    int E = in_sizes[3];
    int N = in_sizes[0] / HCH;
    int d_in_dim = in_sizes[6] / (4 * HCH);   // 781

    uint8_t* w = (uint8_t*)d_ws;
    size_t off = 0;
    short* W0t  = (short*)(w + off); off += (size_t)4 * 25 * 256 * 32 * 2;
    short* Wht  = (short*)(w + off); off += (size_t)4 * 3 * 8 * 256 * 32 * 2;
    float* sc   = (float*)(w + off); off += 4096 * 4;
    float* of   = (float*)(w + off); off += 4096 * 4;
    int*   lists= (int*)(w + off);   off += (size_t)4 * E * 4;
    int*   cnt  = (int*)(w + off);   off += 16;
    short* node_bf = (short*)(w + off); off += (size_t)N * HCH * 2;
    short* geo_bf  = (short*)(w + off); off += (size_t)E * 32 * 2;

    float* out = (float*)d_out;
    int n4 = out_size / 4;
    k_zero<<<(n4 + 255) / 256, 256, 0, stream>>>((float4*)out, n4, cnt);

    int nb_node = N / 8;                 // N*256 elems / (256 thr * 8)
    int nb_geo  = (4 * E + 255) / 256;
    int nb_cmp  = (E + 255) / 256;
    k_prep<<<100 + 96 + 16 + nb_node + nb_geo + nb_cmp, 256, 0, stream>>>(
        W0, Wh, b0, bh, gm, bt, mn, vr, att, node, geo, edxij, edxjk, neip,
        W0t, Wht, sc, of, node_bf, geo_bf, lists, cnt, E, d_in_dim, nb_node, nb_geo);

    int T = (E >> 6) + 8;
    k_main<<<T, 512, 0, stream>>>(node_bf, geo_bf, eidx, W0t, Wht,
                                  sc, of, lists, cnt, out, E);
}